// Round 1
// baseline (1555.221 us; speedup 1.0000x reference)
//
#include <hip/hip_runtime.h>

// ICNN_net_1503238553972 — fully-fused fp32 implementation.
// Per block: 64 rows. LDS (64KB): two 64x128 h-tiles (swizzled) for the f_hat
// MLP, then overlaid V-phase buffers a1/a2/a3 (pad 66) + small scalars.
// Thread map (f_hat GEMM): rows r = tx+16i (i<4), cols j = ty*8..ty*8+7.
//   -> each wave covers 32 cols => 16KB W traffic/wave/layer, broadcast loads.
// h swizzle: element (r,k) stored at r*128 + ((k/4 + r)&31)*4 + k%4
//   -> stride-128 rows stop aliasing to one bank (<=2-way on reads).

#define NPTS 500000
#define GRID_BLKS ((NPTS + 63) / 64)

__device__ __forceinline__ float srelu(float x){
  float c = fminf(fmaxf(x, 0.f), 1.f);
  return c * fmaf(-0.5f, c, x);           // 0 | x^2/2 | x-0.5
}
__device__ __forceinline__ float sreluD(float x){
  return fminf(fmaxf(x, 0.f), 1.f);       // 0 | x | 1
}
__device__ __forceinline__ float lrelu(float x){
  return fmaxf(x, 0.01f * x);
}

__device__ __forceinline__ void gemm128(const float* hin, float* hout,
    const float* __restrict__ W, const float* __restrict__ B, int tx, int ty)
{
  const int j0 = ty * 8;
  float acc[4][8];
#pragma unroll
  for (int i = 0; i < 4; ++i)
#pragma unroll
    for (int j = 0; j < 8; ++j) acc[i][j] = 0.f;

#pragma unroll 2
  for (int k0 = 0; k0 < 128; k0 += 4){
    const int kq = k0 >> 2;
    float4 a[4];
#pragma unroll
    for (int i = 0; i < 4; ++i){
      const int r = tx + 16*i;
      a[i] = *(const float4*)(hin + r*128 + (((kq + r) & 31) << 2));
    }
#pragma unroll
    for (int j = 0; j < 8; ++j){
      float4 w = *(const float4*)(W + (j0 + j)*128 + k0);
#pragma unroll
      for (int i = 0; i < 4; ++i)
        acc[i][j] = fmaf(a[i].x, w.x, fmaf(a[i].y, w.y,
                    fmaf(a[i].z, w.z, fmaf(a[i].w, w.w, acc[i][j]))));
    }
  }
  float4 b0 = *(const float4*)(B + j0);
  float4 b1 = *(const float4*)(B + j0 + 4);
  const int q0 = j0 >> 2;
#pragma unroll
  for (int i = 0; i < 4; ++i){
    const int r = tx + 16*i;
    float4 o0, o1;
    o0.x = lrelu(acc[i][0] + b0.x); o0.y = lrelu(acc[i][1] + b0.y);
    o0.z = lrelu(acc[i][2] + b0.z); o0.w = lrelu(acc[i][3] + b0.w);
    o1.x = lrelu(acc[i][4] + b1.x); o1.y = lrelu(acc[i][5] + b1.y);
    o1.z = lrelu(acc[i][6] + b1.z); o1.w = lrelu(acc[i][7] + b1.w);
    *(float4*)(hout + r*128 + (((q0     + r) & 31) << 2)) = o0;
    *(float4*)(hout + r*128 + (((q0 + 1 + r) & 31) << 2)) = o1;
  }
}

__global__ __launch_bounds__(256, 2) void icnn_kernel(
  const float* __restrict__ X,  const float* __restrict__ Xst,
  const float* __restrict__ Vl1, const float* __restrict__ V2x, const float* __restrict__ V2z,
  const float* __restrict__ V3x, const float* __restrict__ V3z,
  const float* __restrict__ Vfx, const float* __restrict__ Vfz,
  const float* __restrict__ f1w, const float* __restrict__ f1b,
  const float* __restrict__ f2w, const float* __restrict__ f2b,
  const float* __restrict__ f3w, const float* __restrict__ f3b,
  const float* __restrict__ f4w, const float* __restrict__ f4b,
  const float* __restrict__ f5w, const float* __restrict__ f5b,
  const float* __restrict__ ffw, const float* __restrict__ ffb,
  float* __restrict__ out)
{
  __shared__ float smem[16384];              // 64 KB
  const int t   = threadIdx.x;
  const int blk = blockIdx.x;
  float* const HA = smem;                    // [64][128] swizzled
  float* const HB = smem + 8192;             // [64][128] swizzled (also XS at start)
  float* const A1 = smem;                    // [64][66]  V pre-acts (overlay HA)
  float* const A2 = smem + 4224;             // [64][66]
  float* const A3 = smem + 8448;             // [64][66]  (overlay HB)
  float* const FH = smem + 12672;            // [64][2] f_hat
  float* const DS = smem + 12800;            // [64][2] d = X - Xstable
  float* const SF = smem + 12928;            // [64]  sigma'(zf)*sigma'(af)
  float* const VV = smem + 12992;            // [64]  V
  float* const GD = smem + 13056;            // [64][2] gradV

  const int tx = t & 15;
  const int ty = t >> 4;

  // ---- stage X into XS (= HB[0:128]) ----
  if (t < 128){
    const int gi = blk*128 + t;
    HB[t] = (gi < NPTS*2) ? X[gi] : 0.f;
  }
  __syncthreads();

  // ---- f_hat layer 1 (K=2): XS -> HA ----
  {
    const int j0 = ty * 8;
    const int q0 = j0 >> 2;
#pragma unroll
    for (int i = 0; i < 4; ++i){
      const int r = tx + 16*i;
      const float x0 = HB[r*2], x1 = HB[r*2 + 1];
      float ov[8];
#pragma unroll
      for (int j = 0; j < 8; ++j){
        float v = fmaf(x0, f1w[(j0+j)*2], fmaf(x1, f1w[(j0+j)*2 + 1], f1b[j0+j]));
        ov[j] = lrelu(v);
      }
      float4 o0 = make_float4(ov[0], ov[1], ov[2], ov[3]);
      float4 o1 = make_float4(ov[4], ov[5], ov[6], ov[7]);
      *(float4*)(HA + r*128 + (((q0     + r) & 31) << 2)) = o0;
      *(float4*)(HA + r*128 + (((q0 + 1 + r) & 31) << 2)) = o1;
    }
  }
  __syncthreads();
  gemm128(HA, HB, f2w, f2b, tx, ty); __syncthreads();
  gemm128(HB, HA, f3w, f3b, tx, ty); __syncthreads();
  gemm128(HA, HB, f4w, f4b, tx, ty); __syncthreads();
  gemm128(HB, HA, f5w, f5b, tx, ty); __syncthreads();

  // ---- f_hat head (h5 in HA) + stage d ----
  if (t < 128){
    const int r = t >> 1, c = t & 1;
    float s = 0.f;
#pragma unroll 8
    for (int kk = 0; kk < 32; ++kk){
      float4 h = *(const float4*)(HA + r*128 + (((kk + r) & 31) << 2));
      float4 w = *(const float4*)(ffw + c*128 + kk*4);
      s = fmaf(h.x, w.x, fmaf(h.y, w.y, fmaf(h.z, w.z, fmaf(h.w, w.w, s))));
    }
    FH[t] = s + ffb[c];
  } else {
    const int i  = t - 128;
    const int gi = blk*128 + i;
    DS[i] = (gi < NPTS*2) ? (X[gi] - Xst[gi]) : 0.f;
  }
  __syncthreads();

  // ================= V network =================
  const int jv = ty * 4;
  float d0[4], d1[4];
#pragma unroll
  for (int i = 0; i < 4; ++i){
    const int r = tx + 16*i;
    d0[i] = DS[r*2]; d1[i] = DS[r*2 + 1];
  }

  // a1 = Vl1 @ d   (pre-act, overlays HA — h5 is dead now)
#pragma unroll
  for (int j = 0; j < 4; ++j){
    const float w0 = Vl1[(jv+j)*2], w1 = Vl1[(jv+j)*2 + 1];
#pragma unroll
    for (int i = 0; i < 4; ++i){
      const int r = tx + 16*i;
      A1[r*66 + jv + j] = fmaf(d0[i], w0, d1[i] * w1);
    }
  }
  __syncthreads();

  // a2 = V2x@d + V2z@srelu(a1)
  {
    float acc[4][4];
#pragma unroll
    for (int i = 0; i < 4; ++i)
#pragma unroll
      for (int j = 0; j < 4; ++j) acc[i][j] = 0.f;
    for (int k0 = 0; k0 < 64; k0 += 2){
      float za[4][2];
#pragma unroll
      for (int i = 0; i < 4; ++i){
        const int r = tx + 16*i;
        float2 v = *(const float2*)(A1 + r*66 + k0);
        za[i][0] = srelu(v.x); za[i][1] = srelu(v.y);
      }
#pragma unroll
      for (int j = 0; j < 4; ++j){
        float2 w = *(const float2*)(V2z + (jv+j)*64 + k0);
#pragma unroll
        for (int i = 0; i < 4; ++i)
          acc[i][j] = fmaf(za[i][0], w.x, fmaf(za[i][1], w.y, acc[i][j]));
      }
    }
#pragma unroll
    for (int j = 0; j < 4; ++j){
      const float w0 = V2x[(jv+j)*2], w1 = V2x[(jv+j)*2 + 1];
#pragma unroll
      for (int i = 0; i < 4; ++i){
        const int r = tx + 16*i;
        A2[r*66 + jv + j] = fmaf(d0[i], w0, fmaf(d1[i], w1, acc[i][j]));
      }
    }
  }
  __syncthreads();

  // a3 = V3x@d + V3z@srelu(a2)
  {
    float acc[4][4];
#pragma unroll
    for (int i = 0; i < 4; ++i)
#pragma unroll
      for (int j = 0; j < 4; ++j) acc[i][j] = 0.f;
    for (int k0 = 0; k0 < 64; k0 += 2){
      float za[4][2];
#pragma unroll
      for (int i = 0; i < 4; ++i){
        const int r = tx + 16*i;
        float2 v = *(const float2*)(A2 + r*66 + k0);
        za[i][0] = srelu(v.x); za[i][1] = srelu(v.y);
      }
#pragma unroll
      for (int j = 0; j < 4; ++j){
        float2 w = *(const float2*)(V3z + (jv+j)*64 + k0);
#pragma unroll
        for (int i = 0; i < 4; ++i)
          acc[i][j] = fmaf(za[i][0], w.x, fmaf(za[i][1], w.y, acc[i][j]));
      }
    }
#pragma unroll
    for (int j = 0; j < 4; ++j){
      const float w0 = V3x[(jv+j)*2], w1 = V3x[(jv+j)*2 + 1];
#pragma unroll
      for (int i = 0; i < 4; ++i){
        const int r = tx + 16*i;
        A3[r*66 + jv + j] = fmaf(d0[i], w0, fmaf(d1[i], w1, acc[i][j]));
      }
    }
  }
  __syncthreads();

  // af, zf, V, sf  (one wave, one row per lane)
  if (t < 64){
    float s = 0.f;
#pragma unroll 8
    for (int k = 0; k < 64; ++k)
      s = fmaf(srelu(A3[t*66 + k]), Vfz[k], s);
    const float dd0 = DS[t*2], dd1 = DS[t*2 + 1];
    const float af = fmaf(Vfx[0], dd0, fmaf(Vfx[1], dd1, s));
    const float zf = srelu(af);
    VV[t] = srelu(zf) + 0.01f * fmaf(dd0, dd0, dd1*dd1);
    SF[t] = sreluD(zf) * sreluD(af);
  }
  __syncthreads();

  // ga3 = sf * Vfz * srelu'(a3)   (in place)
#pragma unroll
  for (int i = 0; i < 4; ++i){
    const int r = tx + 16*i;
    const float sfr = SF[r];
#pragma unroll
    for (int j = 0; j < 4; ++j){
      const int idx = r*66 + jv + j;
      A3[idx] = sfr * Vfz[jv+j] * sreluD(A3[idx]);
    }
  }
  __syncthreads();

  // ga2 = (V3z^T @ ga3) * srelu'(a2)   (in place over A2)
  {
    float acc[4][4];
#pragma unroll
    for (int i = 0; i < 4; ++i)
#pragma unroll
      for (int j = 0; j < 4; ++j) acc[i][j] = 0.f;
#pragma unroll 4
    for (int j = 0; j < 64; ++j){
      float4 w = *(const float4*)(V3z + j*64 + jv);
      float g[4];
#pragma unroll
      for (int i = 0; i < 4; ++i) g[i] = A3[(tx + 16*i)*66 + j];
#pragma unroll
      for (int i = 0; i < 4; ++i){
        acc[i][0] = fmaf(g[i], w.x, acc[i][0]);
        acc[i][1] = fmaf(g[i], w.y, acc[i][1]);
        acc[i][2] = fmaf(g[i], w.z, acc[i][2]);
        acc[i][3] = fmaf(g[i], w.w, acc[i][3]);
      }
    }
#pragma unroll
    for (int i = 0; i < 4; ++i){
      const int r = tx + 16*i;
#pragma unroll
      for (int j = 0; j < 4; ++j){
        const int idx = r*66 + jv + j;
        A2[idx] = acc[i][j] * sreluD(A2[idx]);
      }
    }
  }
  __syncthreads();

  // ga1 = (V2z^T @ ga2) * srelu'(a1)   (in place over A1)
  {
    float acc[4][4];
#pragma unroll
    for (int i = 0; i < 4; ++i)
#pragma unroll
      for (int j = 0; j < 4; ++j) acc[i][j] = 0.f;
#pragma unroll 4
    for (int j = 0; j < 64; ++j){
      float4 w = *(const float4*)(V2z + j*64 + jv);
      float g[4];
#pragma unroll
      for (int i = 0; i < 4; ++i) g[i] = A2[(tx + 16*i)*66 + j];
#pragma unroll
      for (int i = 0; i < 4; ++i){
        acc[i][0] = fmaf(g[i], w.x, acc[i][0]);
        acc[i][1] = fmaf(g[i], w.y, acc[i][1]);
        acc[i][2] = fmaf(g[i], w.z, acc[i][2]);
        acc[i][3] = fmaf(g[i], w.w, acc[i][3]);
      }
    }
#pragma unroll
    for (int i = 0; i < 4; ++i){
      const int r = tx + 16*i;
#pragma unroll
      for (int j = 0; j < 4; ++j){
        const int idx = r*66 + jv + j;
        A1[idx] = acc[i][j] * sreluD(A1[idx]);
      }
    }
  }
  __syncthreads();

  // gradV: gd[r][c] = sf*Vfx[c] + 2*TOL*d[c] + sum_j (V3x+V2x+Vl1)^T @ ga*
  if (t < 128){
    const int r = t >> 1, c = t & 1;
    float g = fmaf(0.02f, DS[r*2 + c], SF[r] * Vfx[c]);
#pragma unroll 4
    for (int j = 0; j < 64; ++j){
      g = fmaf(V3x[j*2 + c], A3[r*66 + j],
          fmaf(V2x[j*2 + c], A2[r*66 + j],
          fmaf(Vl1[j*2 + c], A1[r*66 + j], g)));
    }
    GD[t] = g;
  }
  __syncthreads();

  // epilogue: f = f_hat - gradV * relu(f_hat.gradV + alpha*V)/(|gradV|^2+eps)
  if (t < 64){
    const int row = blk*64 + t;
    if (row < NPTS){
      const float g0 = GD[t*2], g1 = GD[t*2 + 1];
      const float fh0 = FH[t*2], fh1 = FH[t*2 + 1];
      const float Vn  = fmaf(g0, g0, g1*g1);
      const float fhV = fmaf(fh0, g0, fh1*g1);
      const float num = fmaf(0.1f, VV[t], fhV);
      const float fm  = fmaxf(num, 0.f) / (Vn + 1e-10f);
      float2 o;
      o.x = fmaf(-g0, fm, fh0);
      o.y = fmaf(-g1, fm, fh1);
      *(float2*)(out + row*2) = o;
    }
  }
}

extern "C" void kernel_launch(void* const* d_in, const int* in_sizes, int n_in,
                              void* d_out, int out_size, void* d_ws, size_t ws_size,
                              hipStream_t stream)
{
  const float* X   = (const float*)d_in[0];
  const float* Xst = (const float*)d_in[1];
  const float* Vl1 = (const float*)d_in[2];
  const float* V2x = (const float*)d_in[3];
  const float* V2z = (const float*)d_in[4];
  const float* V3x = (const float*)d_in[5];
  const float* V3z = (const float*)d_in[6];
  const float* Vfx = (const float*)d_in[7];
  const float* Vfz = (const float*)d_in[8];
  const float* f1w = (const float*)d_in[9];
  const float* f1b = (const float*)d_in[10];
  const float* f2w = (const float*)d_in[11];
  const float* f2b = (const float*)d_in[12];
  const float* f3w = (const float*)d_in[13];
  const float* f3b = (const float*)d_in[14];
  const float* f4w = (const float*)d_in[15];
  const float* f4b = (const float*)d_in[16];
  const float* f5w = (const float*)d_in[17];
  const float* f5b = (const float*)d_in[18];
  const float* ffw = (const float*)d_in[19];
  const float* ffb = (const float*)d_in[20];

  icnn_kernel<<<GRID_BLKS, 256, 0, stream>>>(
      X, Xst, Vl1, V2x, V2z, V3x, V3z, Vfx, Vfz,
      f1w, f1b, f2w, f2b, f3w, f3b, f4w, f4b, f5w, f5b, ffw, ffb,
      (float*)d_out);
}

// Round 2
// 755.233 us; speedup vs baseline: 2.0593x; 2.0593x over previous
//
#include <hip/hip_runtime.h>

// ICNN_net_1503238553972 — round 2: f_hat 128x128 layers on fp16 MFMA,
// V-network fp32 VALU with z-buffers (no srelu recompute in k-loops).
//
// Per block: 64 rows, 256 threads (4 waves). LDS 64KB:
//   f_hat phase: WS = f16 W [128][128] swizzled (32KB) | HA,HB = f16 h [64][128] (16KB ea)
//   V phase overlay: Z1/Z2/Z3 = f32 [64][66] + small tail buffers.
// MFMA GEMM2: D[o][r] = sum_k W[o][k] h[r][k]; wave w owns out-channels 32w..32w+31.
//   A-frag lane l: W[w*32+mt*16+(l&15)][kt*32+(l>>4)*8+j]  (row-major 16B)
//   B-frag lane l: h[nt*16+(l&15)][kt*32+(l>>4)*8+j]       (row-major 16B)
//   D lane l: D[o=mt*16+(l>>4)*4+reg][r=nt*16+(l&15)] -> 4 consecutive out-chans
//             = 8B row-major f16 write for the next layer's input.
// Swizzle: 16B chunk c of row r stored at phys chunk (c ^ (r&15)) -> 2-way max.

typedef _Float16 v8h __attribute__((ext_vector_type(8)));
typedef _Float16 v4h __attribute__((ext_vector_type(4)));
typedef float v4f __attribute__((ext_vector_type(4)));

#define NPTS 500000
#define GRID_BLKS ((NPTS + 63) / 64)

__device__ __forceinline__ float srelu(float x){
  float c = fminf(fmaxf(x, 0.f), 1.f);
  return c * fmaf(-0.5f, c, x);           // 0 | x^2/2 | x-0.5
}
__device__ __forceinline__ float sreluD(float x){
  return fminf(fmaxf(x, 0.f), 1.f);       // 0 | x | 1
}
__device__ __forceinline__ float lrelu(float x){
  return fmaxf(x, 0.01f * x);
}
// recover srelu'(a) from z=srelu(a): a in (0,1): z=a^2/2 -> sqrt(2z)=a; a>=1: 2z>=1.
__device__ __forceinline__ float sreluD_from_z(float z){
  return fminf(__builtin_sqrtf(2.f * z), 1.f);
}

// stage one 128x128 fp32 weight matrix into LDS as swizzled f16
__device__ __forceinline__ void stage_w(_Float16* WS, const float* __restrict__ Wg, int t){
  const int rw = t >> 1, hs = t & 1, rs = rw & 15;
#pragma unroll
  for (int c8 = 0; c8 < 8; ++c8){
    const int c = hs*8 + c8;
    const float4 f0 = *(const float4*)(Wg + rw*128 + c*8);
    const float4 f1 = *(const float4*)(Wg + rw*128 + c*8 + 4);
    v8h hv;
    hv[0]=(_Float16)f0.x; hv[1]=(_Float16)f0.y; hv[2]=(_Float16)f0.z; hv[3]=(_Float16)f0.w;
    hv[4]=(_Float16)f1.x; hv[5]=(_Float16)f1.y; hv[6]=(_Float16)f1.z; hv[7]=(_Float16)f1.w;
    *(v8h*)(WS + rw*128 + ((c ^ rs) << 3)) = hv;
  }
}

__device__ __forceinline__ void layer_mfma(const _Float16* WS, const _Float16* hin,
    _Float16* hout, const float* __restrict__ bias, int w, int lm, int q)
{
  v4f acc[2][4];
#pragma unroll
  for (int mt = 0; mt < 2; ++mt)
#pragma unroll
    for (int nt = 0; nt < 4; ++nt) acc[mt][nt] = (v4f){0.f, 0.f, 0.f, 0.f};

#pragma unroll
  for (int kt = 0; kt < 4; ++kt){
    const int sw = ((kt*4 + q) ^ lm) << 3;
    v8h A0 = *(const v8h*)(WS + (w*32      + lm)*128 + sw);
    v8h A1 = *(const v8h*)(WS + (w*32 + 16 + lm)*128 + sw);
    v8h B0 = *(const v8h*)(hin + (     lm)*128 + sw);
    v8h B1 = *(const v8h*)(hin + (16 + lm)*128 + sw);
    v8h B2 = *(const v8h*)(hin + (32 + lm)*128 + sw);
    v8h B3 = *(const v8h*)(hin + (48 + lm)*128 + sw);
    acc[0][0] = __builtin_amdgcn_mfma_f32_16x16x32_f16(A0, B0, acc[0][0], 0, 0, 0);
    acc[0][1] = __builtin_amdgcn_mfma_f32_16x16x32_f16(A0, B1, acc[0][1], 0, 0, 0);
    acc[0][2] = __builtin_amdgcn_mfma_f32_16x16x32_f16(A0, B2, acc[0][2], 0, 0, 0);
    acc[0][3] = __builtin_amdgcn_mfma_f32_16x16x32_f16(A0, B3, acc[0][3], 0, 0, 0);
    acc[1][0] = __builtin_amdgcn_mfma_f32_16x16x32_f16(A1, B0, acc[1][0], 0, 0, 0);
    acc[1][1] = __builtin_amdgcn_mfma_f32_16x16x32_f16(A1, B1, acc[1][1], 0, 0, 0);
    acc[1][2] = __builtin_amdgcn_mfma_f32_16x16x32_f16(A1, B2, acc[1][2], 0, 0, 0);
    acc[1][3] = __builtin_amdgcn_mfma_f32_16x16x32_f16(A1, B3, acc[1][3], 0, 0, 0);
  }

#pragma unroll
  for (int mt = 0; mt < 2; ++mt){
    const int o0 = w*32 + mt*16 + q*4;
    const v4f bv = *(const v4f*)(bias + o0);
    const int cphys = (((o0 >> 3) ^ lm) << 3) + (o0 & 7);
#pragma unroll
    for (int nt = 0; nt < 4; ++nt){
      const int r = nt*16 + lm;
      v4h hv;
      hv[0] = (_Float16)lrelu(acc[mt][nt][0] + bv[0]);
      hv[1] = (_Float16)lrelu(acc[mt][nt][1] + bv[1]);
      hv[2] = (_Float16)lrelu(acc[mt][nt][2] + bv[2]);
      hv[3] = (_Float16)lrelu(acc[mt][nt][3] + bv[3]);
      *(v4h*)(hout + r*128 + cphys) = hv;
    }
  }
}

__global__ __launch_bounds__(256, 2) void icnn_kernel(
  const float* __restrict__ X,  const float* __restrict__ Xst,
  const float* __restrict__ Vl1, const float* __restrict__ V2x, const float* __restrict__ V2z,
  const float* __restrict__ V3x, const float* __restrict__ V3z,
  const float* __restrict__ Vfx, const float* __restrict__ Vfz,
  const float* __restrict__ f1w, const float* __restrict__ f1b,
  const float* __restrict__ f2w, const float* __restrict__ f2b,
  const float* __restrict__ f3w, const float* __restrict__ f3b,
  const float* __restrict__ f4w, const float* __restrict__ f4b,
  const float* __restrict__ f5w, const float* __restrict__ f5b,
  const float* __restrict__ ffw, const float* __restrict__ ffb,
  float* __restrict__ out)
{
  __shared__ float smem[16384];              // 64 KB
  const int t   = threadIdx.x;
  const int blk = blockIdx.x;

  _Float16* const WS = (_Float16*)smem;            // [128][128] f16 swizzled (32KB)
  _Float16* const HA = (_Float16*)(smem + 8192);   // [64][128] f16 swizzled (16KB)
  _Float16* const HB = (_Float16*)(smem + 12288);  // [64][128] f16 swizzled (16KB)
  // V-phase overlays (written only after their f_hat-phase aliases are dead):
  float* const Z1 = smem;                    // [64][66] f32
  float* const Z2 = smem + 4224;             // [64][66]
  float* const Z3 = smem + 8448;             // [64][66]
  float* const GD = smem + 15872;            // [64][2]
  float* const FH = smem + 16000;            // [64][2]
  float* const DS = smem + 16128;            // [64][2]
  float* const SF = smem + 16256;            // [64]
  float* const VV = smem + 16320;            // [64]

  const int l  = t & 63;
  const int w  = t >> 6;
  const int lm = l & 15;
  const int q  = l >> 4;

  // ---- layer 1 (K=2, VALU) -> HA, and stage W2 ----
  {
    const int r = t & 63, cg = t >> 6, rs = r & 15;
    int rg = blk*64 + r; if (rg > NPTS-1) rg = NPTS-1;
    const float2 x = *(const float2*)(X + rg*2);
#pragma unroll
    for (int cc = 0; cc < 4; ++cc){
      const int c = cg*4 + cc;
      v8h hv;
#pragma unroll
      for (int j = 0; j < 8; ++j){
        const int oc = c*8 + j;
        const float2 wv = *(const float2*)(f1w + oc*2);
        hv[j] = (_Float16)lrelu(fmaf(x.x, wv.x, fmaf(x.y, wv.y, f1b[oc])));
      }
      *(v8h*)(HA + r*128 + ((c ^ rs) << 3)) = hv;
    }
  }
  stage_w(WS, f2w, t);
  __syncthreads();
  layer_mfma(WS, HA, HB, f2b, w, lm, q);  __syncthreads();
  stage_w(WS, f3w, t);                    __syncthreads();
  layer_mfma(WS, HB, HA, f3b, w, lm, q);  __syncthreads();
  stage_w(WS, f4w, t);                    __syncthreads();
  layer_mfma(WS, HA, HB, f4b, w, lm, q);  __syncthreads();
  stage_w(WS, f5w, t);                    __syncthreads();
  layer_mfma(WS, HB, HA, f5b, w, lm, q);  __syncthreads();

  // ---- f_hat head (h5 in HA) + stage d ----
  if (t < 128){
    const int r = t >> 1, ci = t & 1, rs = r & 15;
    float s = 0.f;
#pragma unroll 4
    for (int ck = 0; ck < 16; ++ck){
      v8h h = *(const v8h*)(HA + r*128 + ((ck ^ rs) << 3));
      const float* wp = ffw + ci*128 + ck*8;
#pragma unroll
      for (int j = 0; j < 8; ++j) s = fmaf((float)h[j], wp[j], s);
    }
    FH[t] = s + ffb[ci];
  } else {
    const int i = t - 128;
    int gi = blk*128 + i; if (gi > 2*NPTS-1) gi = 2*NPTS-1;
    DS[i] = X[gi] - Xst[gi];
  }
  __syncthreads();

  // ================= V network (fp32 VALU, z-buffers) =================
  const int tx = t & 15;
  const int ty = t >> 4;
  const int jv = ty * 4;
  float d0[4], d1[4];
#pragma unroll
  for (int i = 0; i < 4; ++i){
    const int r = tx + 16*i;
    d0[i] = DS[r*2]; d1[i] = DS[r*2 + 1];
  }

  // z1 = srelu(Vl1 @ d)     (Z1 overlays WS only — safe now)
#pragma unroll
  for (int j = 0; j < 4; ++j){
    const float w0 = Vl1[(jv+j)*2], w1 = Vl1[(jv+j)*2 + 1];
#pragma unroll
    for (int i = 0; i < 4; ++i){
      const int r = tx + 16*i;
      Z1[r*66 + jv + j] = srelu(fmaf(d0[i], w0, d1[i] * w1));
    }
  }
  __syncthreads();

  // z2 = srelu(V2x@d + V2z@z1)   (FH already extracted from HA)
  {
    float acc[4][4];
#pragma unroll
    for (int i = 0; i < 4; ++i)
#pragma unroll
      for (int j = 0; j < 4; ++j) acc[i][j] = 0.f;
    for (int k0 = 0; k0 < 64; k0 += 2){
      float2 z[4];
#pragma unroll
      for (int i = 0; i < 4; ++i) z[i] = *(const float2*)(Z1 + (tx + 16*i)*66 + k0);
#pragma unroll
      for (int j = 0; j < 4; ++j){
        const float2 wv = *(const float2*)(V2z + (jv+j)*64 + k0);
#pragma unroll
        for (int i = 0; i < 4; ++i)
          acc[i][j] = fmaf(z[i].x, wv.x, fmaf(z[i].y, wv.y, acc[i][j]));
      }
    }
#pragma unroll
    for (int j = 0; j < 4; ++j){
      const float w0 = V2x[(jv+j)*2], w1 = V2x[(jv+j)*2 + 1];
#pragma unroll
      for (int i = 0; i < 4; ++i){
        const int r = tx + 16*i;
        Z2[r*66 + jv + j] = srelu(fmaf(d0[i], w0, fmaf(d1[i], w1, acc[i][j])));
      }
    }
  }
  __syncthreads();

  // z3 = srelu(V3x@d + V3z@z2)
  {
    float acc[4][4];
#pragma unroll
    for (int i = 0; i < 4; ++i)
#pragma unroll
      for (int j = 0; j < 4; ++j) acc[i][j] = 0.f;
    for (int k0 = 0; k0 < 64; k0 += 2){
      float2 z[4];
#pragma unroll
      for (int i = 0; i < 4; ++i) z[i] = *(const float2*)(Z2 + (tx + 16*i)*66 + k0);
#pragma unroll
      for (int j = 0; j < 4; ++j){
        const float2 wv = *(const float2*)(V3z + (jv+j)*64 + k0);
#pragma unroll
        for (int i = 0; i < 4; ++i)
          acc[i][j] = fmaf(z[i].x, wv.x, fmaf(z[i].y, wv.y, acc[i][j]));
      }
    }
#pragma unroll
    for (int j = 0; j < 4; ++j){
      const float w0 = V3x[(jv+j)*2], w1 = V3x[(jv+j)*2 + 1];
#pragma unroll
      for (int i = 0; i < 4; ++i){
        const int r = tx + 16*i;
        Z3[r*66 + jv + j] = srelu(fmaf(d0[i], w0, fmaf(d1[i], w1, acc[i][j])));
      }
    }
  }
  __syncthreads();

  // af, zf, V, sf  (one wave, one row per lane)
  if (t < 64){
    float s = 0.f;
    for (int k = 0; k < 64; k += 2){
      const float2 z = *(const float2*)(Z3 + t*66 + k);
      s = fmaf(z.x, Vfz[k], fmaf(z.y, Vfz[k+1], s));
    }
    const float dd0 = DS[t*2], dd1 = DS[t*2 + 1];
    const float af = fmaf(Vfx[0], dd0, fmaf(Vfx[1], dd1, s));
    const float zf = srelu(af);
    VV[t] = srelu(zf) + 0.01f * fmaf(dd0, dd0, dd1*dd1);
    SF[t] = sreluD(zf) * sreluD(af);
  }
  __syncthreads();

  // ga3 = sf * Vfz * srelu'(a3)   (in place over Z3)
#pragma unroll
  for (int i = 0; i < 4; ++i){
    const int r = tx + 16*i;
    const float sfr = SF[r];
#pragma unroll
    for (int j = 0; j < 4; ++j){
      const int idx = r*66 + jv + j;
      Z3[idx] = sfr * Vfz[jv+j] * sreluD_from_z(Z3[idx]);
    }
  }
  __syncthreads();

  // ga2 = (V3z^T @ ga3) * srelu'(a2)   (in place over Z2)
  {
    float acc[4][4];
#pragma unroll
    for (int i = 0; i < 4; ++i)
#pragma unroll
      for (int j = 0; j < 4; ++j) acc[i][j] = 0.f;
#pragma unroll 4
    for (int j = 0; j < 64; ++j){
      const float4 wv = *(const float4*)(V3z + j*64 + jv);
      float g[4];
#pragma unroll
      for (int i = 0; i < 4; ++i) g[i] = Z3[(tx + 16*i)*66 + j];
#pragma unroll
      for (int i = 0; i < 4; ++i){
        acc[i][0] = fmaf(g[i], wv.x, acc[i][0]);
        acc[i][1] = fmaf(g[i], wv.y, acc[i][1]);
        acc[i][2] = fmaf(g[i], wv.z, acc[i][2]);
        acc[i][3] = fmaf(g[i], wv.w, acc[i][3]);
      }
    }
#pragma unroll
    for (int i = 0; i < 4; ++i){
      const int r = tx + 16*i;
#pragma unroll
      for (int j = 0; j < 4; ++j){
        const int idx = r*66 + jv + j;
        Z2[idx] = acc[i][j] * sreluD_from_z(Z2[idx]);
      }
    }
  }
  __syncthreads();

  // ga1 = (V2z^T @ ga2) * srelu'(a1)   (in place over Z1)
  {
    float acc[4][4];
#pragma unroll
    for (int i = 0; i < 4; ++i)
#pragma unroll
      for (int j = 0; j < 4; ++j) acc[i][j] = 0.f;
#pragma unroll 4
    for (int j = 0; j < 64; ++j){
      const float4 wv = *(const float4*)(V2z + j*64 + jv);
      float g[4];
#pragma unroll
      for (int i = 0; i < 4; ++i) g[i] = Z2[(tx + 16*i)*66 + j];
#pragma unroll
      for (int i = 0; i < 4; ++i){
        acc[i][0] = fmaf(g[i], wv.x, acc[i][0]);
        acc[i][1] = fmaf(g[i], wv.y, acc[i][1]);
        acc[i][2] = fmaf(g[i], wv.z, acc[i][2]);
        acc[i][3] = fmaf(g[i], wv.w, acc[i][3]);
      }
    }
#pragma unroll
    for (int i = 0; i < 4; ++i){
      const int r = tx + 16*i;
#pragma unroll
      for (int j = 0; j < 4; ++j){
        const int idx = r*66 + jv + j;
        Z1[idx] = acc[i][j] * sreluD_from_z(Z1[idx]);
      }
    }
  }
  __syncthreads();

  // gradV
  if (t < 128){
    const int r = t >> 1, c = t & 1;
    float g = fmaf(0.02f, DS[r*2 + c], SF[r] * Vfx[c]);
#pragma unroll 4
    for (int j = 0; j < 64; ++j){
      g = fmaf(V3x[j*2 + c], Z3[r*66 + j],
          fmaf(V2x[j*2 + c], Z2[r*66 + j],
          fmaf(Vl1[j*2 + c], Z1[r*66 + j], g)));
    }
    GD[t] = g;
  }
  __syncthreads();

  // epilogue
  if (t < 64){
    const int row = blk*64 + t;
    if (row < NPTS){
      const float g0 = GD[t*2], g1 = GD[t*2 + 1];
      const float fh0 = FH[t*2], fh1 = FH[t*2 + 1];
      const float Vn  = fmaf(g0, g0, g1*g1);
      const float fhV = fmaf(fh0, g0, fh1*g1);
      const float num = fmaf(0.1f, VV[t], fhV);
      const float fm  = fmaxf(num, 0.f) / (Vn + 1e-10f);
      float2 o;
      o.x = fmaf(-g0, fm, fh0);
      o.y = fmaf(-g1, fm, fh1);
      *(float2*)(out + row*2) = o;
    }
  }
}

extern "C" void kernel_launch(void* const* d_in, const int* in_sizes, int n_in,
                              void* d_out, int out_size, void* d_ws, size_t ws_size,
                              hipStream_t stream)
{
  const float* X   = (const float*)d_in[0];
  const float* Xst = (const float*)d_in[1];
  const float* Vl1 = (const float*)d_in[2];
  const float* V2x = (const float*)d_in[3];
  const float* V2z = (const float*)d_in[4];
  const float* V3x = (const float*)d_in[5];
  const float* V3z = (const float*)d_in[6];
  const float* Vfx = (const float*)d_in[7];
  const float* Vfz = (const float*)d_in[8];
  const float* f1w = (const float*)d_in[9];
  const float* f1b = (const float*)d_in[10];
  const float* f2w = (const float*)d_in[11];
  const float* f2b = (const float*)d_in[12];
  const float* f3w = (const float*)d_in[13];
  const float* f3b = (const float*)d_in[14];
  const float* f4w = (const float*)d_in[15];
  const float* f4b = (const float*)d_in[16];
  const float* f5w = (const float*)d_in[17];
  const float* f5b = (const float*)d_in[18];
  const float* ffw = (const float*)d_in[19];
  const float* ffb = (const float*)d_in[20];

  icnn_kernel<<<GRID_BLKS, 256, 0, stream>>>(
      X, Xst, Vl1, V2x, V2z, V3x, V3z, Vfx, Vfz,
      f1w, f1b, f2w, f2b, f3w, f3b, f4w, f4b, f5w, f5b, ffw, ffb,
      (float*)d_out);
}